// Round 11
// baseline (286.736 us; speedup 1.0000x reference)
//
#include <hip/hip_runtime.h>
#include <hip/hip_fp16.h>
#include <math.h>

// EM routing, hardcoded geometry: CHILD_SPACE=12, K=3, S=1 -> P=10,
// CHILD_CAPS=16, PARENT_CAPS=O=32, POSE=16, N=4, KTOT=144
#define NB     4
#define P      10
#define P2     100
#define CS     12
#define CCAPS  16
#define KTOT   144
#define O      32
#define POSE   16
#define VSZ    73728          // KTOT*O*POSE elems per (b,p)
#define EPSF   1e-9f
#define LNF    22.2222222222222222f   // 100/(144/32)
#define TWO_PI 6.28318530717958647f
#define NBP    400
#define NKQ    3              // K-chunks per bp
#define KPU    48
#define SUNITS (NBP*NKQ)      // 1200

#define LAM0 0.0005f          // 0.01*(1-0.95)
#define LAM1 0.000975f        // 0.01*(1-0.95^2)
#define LAM2 0.00142625f      // 0.01*(1-0.95^3)

__device__ float g_zz [NBP*KTOT*O];
__device__ float g_m1 [SUNITS*512];
__device__ float g_m2 [SUNITS*512];
__device__ float g_sv [SUNITS*O];

// number of parents covering child coord x (1-D): min(x+1, 3, 12-x)
__device__ __forceinline__ int npar(int x) {
    int a = x + 1, b = CS - x;
    int m = a < 3 ? a : 3;
    return m < b ? m : b;
}

__device__ __forceinline__ void up8(uint4 u, float* f) {
    float2 a = __half22float2(*(__half2*)&u.x);
    float2 b = __half22float2(*(__half2*)&u.y);
    float2 c = __half22float2(*(__half2*)&u.z);
    float2 d = __half22float2(*(__half2*)&u.w);
    f[0] = a.x; f[1] = a.y; f[2] = b.x; f[3] = b.y;
    f[4] = c.x; f[5] = c.y; f[6] = d.x; f[7] = d.y;
}

// ---------------- V: fp32 stats (iter 0, closed-form rr) + fp16 convert ----
// grid 1200 = bp*3 + kq (48 k-rows). 256 thr: tid = ks*128 + q, q = o*4+c4.
__global__ __launch_bounds__(256)
void v_kernel(const float* __restrict__ votes, const float* __restrict__ acts,
              __half* __restrict__ hv)
{
    __shared__ float actl[KPU];
    __shared__ __align__(16) float rrp[KPU*O];
    __shared__ float4 lm1[256];
    __shared__ float4 lm2[256];
    __shared__ float  lss[256];

    const int tid = threadIdx.x;
    const int u   = blockIdx.x;
    const int bp  = u / NKQ;
    const int kq  = u - bp * NKQ;
    const int k0  = kq * KPU;
    const int ks  = tid >> 7;
    const int q   = tid & 127;
    const int o   = q >> 2;

    if (tid < KPU) actl[tid] = acts[bp * KTOT + k0 + tid];
    __syncthreads();

    for (int f = tid; f < KPU * O / 4; f += 256) {
        int kl = f >> 3;
        int kg = k0 + kl, kslot = kg >> 4;
        int kr = kslot / 3, kc = kslot - kr * 3;
        int p = bp % P2, pr = p / P, pc = p - pr * P;
        float ppc = (float)(npar(pr + kr) * npar(pc + kc));
        float r = actl[kl] / (ppc * 32.0f + EPSF);
        ((float4*)rrp)[f] = make_float4(r, r, r, r);
    }
    __syncthreads();

    const float* vb  = votes + (size_t)bp * VSZ + (size_t)(k0 + ks * 24) * 512 + q * 4;
    __half*      hb  = hv    + (size_t)bp * VSZ + (size_t)(k0 + ks * 24) * 512 + q * 4;
    const float* rr0 = rrp + (ks * 24) * O + o;
    float  s  = 0.f;
    float4 m1 = make_float4(0.f, 0.f, 0.f, 0.f);
    float4 m2 = make_float4(0.f, 0.f, 0.f, 0.f);
    #pragma unroll 8
    for (int i = 0; i < 24; ++i) {
        float  rp = rr0[i * O];
        float4 v  = *(const float4*)(vb + i * 512);
        s += rp;
        m1.x += rp * v.x;       m1.y += rp * v.y;
        m1.z += rp * v.z;       m1.w += rp * v.w;
        m2.x += rp * v.x * v.x; m2.y += rp * v.y * v.y;
        m2.z += rp * v.z * v.z; m2.w += rp * v.w * v.w;
        __half2 ha  = __floats2half2_rn(v.x, v.y);
        __half2 hbv = __floats2half2_rn(v.z, v.w);
        uint2 st;
        st.x = *(unsigned int*)&ha;
        st.y = *(unsigned int*)&hbv;
        *(uint2*)(hb + i * 512) = st;
    }
    lm1[tid] = m1; lm2[tid] = m2; lss[tid] = s;
    __syncthreads();

    if (tid < 128) {
        float4 a = lm1[tid], b = lm1[tid + 128];
        m1 = make_float4(a.x + b.x, a.y + b.y, a.z + b.z, a.w + b.w);
        a = lm2[tid]; b = lm2[tid + 128];
        m2 = make_float4(a.x + b.x, a.y + b.y, a.z + b.z, a.w + b.w);
        s = lss[tid] + lss[tid + 128];
        ((float4*)g_m1)[u * 128 + tid] = m1;
        ((float4*)g_m2)[u * 128 + tid] = m2;
        if ((tid & 3) == 0) g_sv[u * O + (tid >> 2)] = s;
    }
}

// ---------------- shared finish computation (tid<128 path) ----------------
__device__ __forceinline__ void finish_bp(int bp, int tid, float lam,
                                          const float* __restrict__ beta_v,
                                          const float* __restrict__ beta_a,
                                          float4& mean, float4& i2,
                                          float& aj, float& lv2out,
                                          float* costl /* [O] LDS */)
{
    const int o = tid >> 2, c4 = tid & 3;
    float4 m1 = make_float4(0.f, 0.f, 0.f, 0.f);
    float4 m2 = make_float4(0.f, 0.f, 0.f, 0.f);
    float  s  = 0.f;
    #pragma unroll
    for (int j = 0; j < NKQ; ++j) {
        float4 a = ((const float4*)g_m1)[(bp * NKQ + j) * 128 + tid];
        float4 b = ((const float4*)g_m2)[(bp * NKQ + j) * 128 + tid];
        m1.x += a.x; m1.y += a.y; m1.z += a.z; m1.w += a.w;
        m2.x += b.x; m2.y += b.y; m2.z += b.z; m2.w += b.w;
        s += g_sv[(bp * NKQ + j) * O + o];
    }
    float denom = s + EPSF;
    mean = make_float4(m1.x / denom, m1.y / denom, m1.z / denom, m1.w / denom);
    float4 var;
    var.x = fmaxf(m2.x / denom - mean.x * mean.x, 1e-30f);
    var.y = fmaxf(m2.y / denom - mean.y * mean.y, 1e-30f);
    var.z = fmaxf(m2.z / denom - mean.z * mean.z, 1e-30f);
    var.w = fmaxf(m2.w / denom - mean.w * mean.w, 1e-30f);
    i2 = make_float4(0.5f / var.x, 0.5f / var.y, 0.5f / var.z, 0.5f / var.w);
    float lve = logf(var.x + EPSF) + logf(var.y + EPSF)
              + logf(var.z + EPSF) + logf(var.w + EPSF);
    float lv2 = logf(TWO_PI * var.x) + logf(TWO_PI * var.y)
              + logf(TWO_PI * var.z) + logf(TWO_PI * var.w);
    lve += __shfl_xor(lve, 1); lve += __shfl_xor(lve, 2);
    lv2 += __shfl_xor(lv2, 1); lv2 += __shfl_xor(lv2, 2);
    lv2out = lv2;
    if (c4 == 0) costl[o] = (16.f * beta_v[o] + 0.5f * lve) * s * LNF;
    __syncthreads();
    float cm = 0.f;
    #pragma unroll
    for (int i = 0; i < O; ++i) cm += costl[i];
    cm *= (1.f / 32.f);
    float sq = 0.f;
    #pragma unroll
    for (int i = 0; i < O; ++i) { float d = costl[i] - cm; sq += d * d; }
    float cstd = sqrtf(sq * (1.f / 32.f));
    aj = 1.f / (1.f + expf(-lam * (beta_a[o] + (cm - costl[o]) / (cstd + EPSF))));
}

// ---------------- ZF16: inline finish + zz from fp16 votes ----------------
// grid 1200. Each block redundantly finishes its bp from the 3 partial slabs
// (cheap), then computes zz for its 48 k-rows. No separate F dispatch.
__global__ __launch_bounds__(256)
void zf16_kernel(const __half* __restrict__ hv,
                 const float* __restrict__ beta_v,
                 const float* __restrict__ beta_a, float lam)
{
    __shared__ float4 ml[128];
    __shared__ float4 il[128];
    __shared__ float  zl[O];
    __shared__ float  costl[O];
    __shared__ __align__(16) float zzl[KPU*O];

    const int tid = threadIdx.x;
    const int u   = blockIdx.x;
    const int bp  = u / NKQ;
    const int kq  = u - bp * NKQ;
    const int k0  = kq * KPU;
    const int ks  = tid >> 6;
    const int qp  = tid & 63;
    const int o   = qp >> 1;
    const int h   = qp & 1;

    // issue the 12 vote loads FIRST (independent of the finish math)
    const __half* vb = hv + (size_t)bp * VSZ + (size_t)(k0 + ks * 12) * 512 + qp * 8;
    uint4 vv[12];
    #pragma unroll
    for (int i = 0; i < 12; ++i) vv[i] = *(const uint4*)(vb + i * 512);

    {
        float4 mean, i2; float aj, lv2;
        if (tid < 128) {
            finish_bp(bp, tid, lam, beta_v, beta_a, mean, i2, aj, lv2, costl);
            ml[tid] = mean; il[tid] = i2;
            if ((tid & 3) == 0)
                zl[tid >> 2] = logf(aj + EPSF) - 0.5f * lv2;
        } else {
            __syncthreads();   // matches the barrier inside finish_bp
        }
    }
    __syncthreads();

    float4 mA = ml[o*4 + h*2], mB = ml[o*4 + h*2 + 1];
    float4 iA = il[o*4 + h*2], iB = il[o*4 + h*2 + 1];
    float  zp = zl[o];
    #pragma unroll
    for (int i = 0; i < 12; ++i) {
        float f[8]; up8(vv[i], f);
        float d0 = f[0]-mA.x, d1 = f[1]-mA.y, d2 = f[2]-mA.z, d3 = f[3]-mA.w;
        float d4 = f[4]-mB.x, d5 = f[5]-mB.y, d6 = f[6]-mB.z, d7 = f[7]-mB.w;
        float t = d0*d0*iA.x + d1*d1*iA.y + d2*d2*iA.z + d3*d3*iA.w
                + d4*d4*iB.x + d5*d5*iB.y + d6*d6*iB.z + d7*d7*iB.w;
        t += __shfl_xor(t, 1);             // sum over 16 pose comps (h pair)
        if (h == 0) zzl[(ks * 12 + i) * O + o] = zp - t;
    }
    __syncthreads();
    float4* dst = (float4*)(g_zz + (size_t)bp * (KTOT * O) + k0 * O);
    for (int f = tid; f < KPU * O / 4; f += 256)
        dst[f] = ((float4*)zzl)[f];
}

// ---------------- SE16: fused segment-softmax + stats partials -------------
// grid 1200 = bp*3 + kq. The block's 48 rr-rows (si = 3kq..3kq+2, cc, o)
// belong to 3 children (cr = pr+kq, cl = pc+i). Gather those children's zz
// from their <=9 parents (L2/L3), softmax, rr' = e*inv*act into LDS, then
// the s16 stats loop with votes preloaded up front.
__global__ __launch_bounds__(256)
void se16_kernel(const __half* __restrict__ hv, const float* __restrict__ acts)
{
    __shared__ __align__(16) float rrp[KPU*O];    // rr' rows (local k = i*16+cc)
    __shared__ float4 lm1[512];
    __shared__ float4 lm2[512];
    __shared__ float  lss[256];

    const int tid = threadIdx.x;
    const int u   = blockIdx.x;
    const int bp  = u / NKQ;
    const int kq  = u - bp * NKQ;
    const int k0  = kq * KPU;
    const int p   = bp % P2;
    const int b   = bp / P2;
    const int pr  = p / P, pc = p - pr * P;

    // stats-phase thread map (used later)
    const int ks  = tid >> 6;
    const int qp  = tid & 63;
    const int o_s = qp >> 1;

    // preload votes first — independent of the softmax phase
    const __half* vb = hv + (size_t)bp * VSZ + (size_t)(k0 + ks * 12) * 512 + qp * 8;
    uint4 vv[12];
    #pragma unroll
    for (int i = 0; i < 12; ++i) vv[i] = *(const uint4*)(vb + i * 512);

    // softmax phase: thread = (ccl, o)
    const int ccl = tid >> 5;       // 0..7
    const int o   = tid & 31;
    const int cr  = pr + kq;        // child row (always valid)

    #pragma unroll
    for (int ci = 0; ci < 3; ++ci) {
        const int cl = pc + ci;     // child col (always valid)
        #pragma unroll
        for (int ccp = 0; ccp < 2; ++ccp) {
            const int cc = ccl + 8 * ccp;
            float zv[9];
            float vmax = -1e30f;
            #pragma unroll
            for (int sip = 0; sip < 9; ++sip) {
                const int krp = sip / 3, kcp = sip - krp * 3;
                const int pr2 = cr - krp, pc2 = cl - kcp;
                float z = -1e30f;
                if (pr2 >= 0 && pr2 < P && pc2 >= 0 && pc2 < P) {
                    const int bp2 = b * P2 + pr2 * P + pc2;
                    z = g_zz[(size_t)bp2 * (KTOT * O) + (sip * CCAPS + cc) * O + o];
                }
                zv[sip] = z;
                vmax = fmaxf(vmax, z);
            }
            vmax = fmaxf(vmax, __shfl_xor(vmax, 1));
            vmax = fmaxf(vmax, __shfl_xor(vmax, 2));
            vmax = fmaxf(vmax, __shfl_xor(vmax, 4));
            vmax = fmaxf(vmax, __shfl_xor(vmax, 8));
            vmax = fmaxf(vmax, __shfl_xor(vmax, 16));   // max over o
            float ps = 0.f;
            #pragma unroll
            for (int sip = 0; sip < 9; ++sip)
                ps += (zv[sip] > -1e29f) ? expf(zv[sip] - vmax) : 0.f;
            ps += __shfl_xor(ps, 1);
            ps += __shfl_xor(ps, 2);
            ps += __shfl_xor(ps, 4);
            ps += __shfl_xor(ps, 8);
            ps += __shfl_xor(ps, 16);                   // sum over o
            const float inv = 1.f / ps;
            // own row: parent bp via slot si = 3kq + ci
            const int si = 3 * kq + ci;
            const float av = acts[bp * KTOT + si * CCAPS + cc];
            const float rp = expf(zv[si] - vmax) * inv * av;
            rrp[(ci * CCAPS + cc) * O + o] = rp;
        }
    }
    __syncthreads();

    // stats phase (s16 hot loop, rr' from LDS)
    const float* rr0 = rrp + (ks * 12) * O + o_s;
    float s = 0.f;
    float m1[8], m2[8];
    #pragma unroll
    for (int j = 0; j < 8; ++j) { m1[j] = 0.f; m2[j] = 0.f; }
    #pragma unroll
    for (int i = 0; i < 12; ++i) {
        float rp = rr0[i * O];
        float f[8]; up8(vv[i], f);
        s += rp;
        #pragma unroll
        for (int j = 0; j < 8; ++j) {
            m1[j] += rp * f[j];
            m2[j] += rp * f[j] * f[j];
        }
    }
    lm1[tid*2]   = make_float4(m1[0], m1[1], m1[2], m1[3]);
    lm1[tid*2+1] = make_float4(m1[4], m1[5], m1[6], m1[7]);
    lm2[tid*2]   = make_float4(m2[0], m2[1], m2[2], m2[3]);
    lm2[tid*2+1] = make_float4(m2[4], m2[5], m2[6], m2[7]);
    lss[tid] = s;
    __syncthreads();

    if (tid < 64) {
        #pragma unroll
        for (int j = 0; j < 2; ++j) {
            float4 a0 = lm1[(tid)*2+j],       a1 = lm1[(64+tid)*2+j];
            float4 a2 = lm1[(128+tid)*2+j],   a3 = lm1[(192+tid)*2+j];
            float4 r = make_float4(a0.x+a1.x+a2.x+a3.x, a0.y+a1.y+a2.y+a3.y,
                                   a0.z+a1.z+a2.z+a3.z, a0.w+a1.w+a2.w+a3.w);
            ((float4*)g_m1)[u * 128 + tid*2 + j] = r;
            float4 b0 = lm2[(tid)*2+j],       b1 = lm2[(64+tid)*2+j];
            float4 b2 = lm2[(128+tid)*2+j],   b3 = lm2[(192+tid)*2+j];
            float4 r2 = make_float4(b0.x+b1.x+b2.x+b3.x, b0.y+b1.y+b2.y+b3.y,
                                    b0.z+b1.z+b2.z+b3.z, b0.w+b1.w+b2.w+b3.w);
            ((float4*)g_m2)[u * 128 + tid*2 + j] = r2;
        }
        float sr = lss[tid] + lss[64+tid] + lss[128+tid] + lss[192+tid];
        if ((tid & 1) == 0) g_sv[u * O + (tid >> 1)] = sr;
    }
}

// ---------------- F_last: finish + write outputs ----------------
__global__ __launch_bounds__(256)
void f_last_kernel(const float* __restrict__ beta_v,
                   const float* __restrict__ beta_a,
                   float* __restrict__ out, float lam)
{
    __shared__ float costl[O];
    const int tid = threadIdx.x;
    const int bp  = blockIdx.x;
    float4 mean, i2; float aj, lv2;
    if (tid < 128) {
        finish_bp(bp, tid, lam, beta_v, beta_a, mean, i2, aj, lv2, costl);
        ((float4*)out)[bp * 128 + tid] = mean;
        if ((tid & 3) == 0)
            out[(size_t)NBP * 512 + bp * O + (tid >> 2)] = aj;
    } else {
        __syncthreads();
    }
}

extern "C" void kernel_launch(void* const* d_in, const int* in_sizes, int n_in,
                              void* d_out, int out_size, void* d_ws, size_t ws_size,
                              hipStream_t stream)
{
    (void)in_sizes; (void)n_in; (void)out_size; (void)ws_size;

    const float* votes = (const float*)d_in[0];
    const float* acts  = (const float*)d_in[1];
    const float* bv    = (const float*)d_in[2];
    const float* ba    = (const float*)d_in[3];
    float* out = (float*)d_out;
    __half* hv = (__half*)d_ws;          // 59 MB fp16 votes copy

    dim3 t(256);
    v_kernel<<<dim3(SUNITS), t, 0, stream>>>(votes, acts, hv);
    zf16_kernel<<<dim3(SUNITS), t, 0, stream>>>(hv, bv, ba, LAM0);
    se16_kernel<<<dim3(SUNITS), t, 0, stream>>>(hv, acts);
    zf16_kernel<<<dim3(SUNITS), t, 0, stream>>>(hv, bv, ba, LAM1);
    se16_kernel<<<dim3(SUNITS), t, 0, stream>>>(hv, acts);
    f_last_kernel<<<dim3(NBP), t, 0, stream>>>(bv, ba, out, LAM2);
}

// Round 12
// 257.347 us; speedup vs baseline: 1.1142x; 1.1142x over previous
//
#include <hip/hip_runtime.h>
#include <hip/hip_fp16.h>
#include <math.h>

// EM routing, hardcoded geometry: CHILD_SPACE=12, K=3, S=1 -> P=10,
// CHILD_CAPS=16, PARENT_CAPS=O=32, POSE=16, N=4, KTOT=144
#define NB     4
#define P      10
#define P2     100
#define CS     12
#define CCAPS  16
#define KTOT   144
#define O      32
#define POSE   16
#define VSZ    73728          // KTOT*O*POSE elems per (b,p)
#define EPSF   1e-9f
#define LNF    22.2222222222222222f   // 100/(144/32)
#define TWO_PI 6.28318530717958647f
#define NBP    400
#define EUNITS (NB*CS*CS*2)   // 1152

#define LAM0 0.0005f          // 0.01*(1-0.95)
#define LAM1 0.000975f        // 0.01*(1-0.95^2)
#define LAM2 0.00142625f      // 0.01*(1-0.95^3)

__device__ float g_zz [NBP*KTOT*O];   // log-posteriors (M output)
__device__ float g_rrp[NBP*KTOT*O];   // rr' = rr * act (E output)

// number of parents covering child coord x (1-D): min(x+1, 3, 12-x)
__device__ __forceinline__ int npar(int x) {
    int a = x + 1, b = CS - x;
    int m = a < 3 ? a : 3;
    return m < b ? m : b;
}

__device__ __forceinline__ void up8(uint4 u, float* f) {
    float2 a = __half22float2(*(__half2*)&u.x);
    float2 b = __half22float2(*(__half2*)&u.y);
    float2 c = __half22float2(*(__half2*)&u.z);
    float2 d = __half22float2(*(__half2*)&u.w);
    f[0] = a.x; f[1] = a.y; f[2] = b.x; f[3] = b.y;
    f[4] = c.x; f[5] = c.y; f[6] = d.x; f[7] = d.y;
}

// =========== V400: iter-0 m_step fully fused (fp32) + fp16 convert ==========
// grid 400 (bp), 512 thr: tid = ks*128 + q, ks=0..3 (36 rows each), q = o*4+c4.
__global__ __launch_bounds__(512)
void v400_kernel(const float* __restrict__ votes, const float* __restrict__ acts,
                 __half* __restrict__ hv,
                 const float* __restrict__ beta_v, const float* __restrict__ beta_a,
                 float lam)
{
    __shared__ float  rr1[KTOT];                  // iter-0 rr' (o-independent)
    __shared__ float4 lm1[512];                   // 8 KB
    __shared__ float4 lm2[512];                   // 8 KB
    __shared__ float  lss[512];
    __shared__ float4 ml[128];
    __shared__ float4 il[128];
    __shared__ float  zl[O];
    __shared__ float  costl[O];
    __shared__ __align__(16) float zzl[KTOT*O];   // 18 KB

    const int tid = threadIdx.x;
    const int bp  = blockIdx.x;
    const int p   = bp % P2;
    const int pr  = p / P, pc = p - pr * P;
    const int ks  = tid >> 7;
    const int q   = tid & 127;
    const int o   = q >> 2;
    const int c4  = q & 3;

    if (tid < KTOT) {
        int kslot = tid >> 4;
        int kr = kslot / 3, kc = kslot - kr * 3;
        float ppc = (float)(npar(pr + kr) * npar(pc + kc));
        rr1[tid] = acts[bp * KTOT + tid] / (ppc * 32.0f + EPSF);
    }
    __syncthreads();

    const float* vb = votes + (size_t)bp * VSZ + (size_t)(ks * 36) * 512 + q * 4;
    __half*      hb = hv    + (size_t)bp * VSZ + (size_t)(ks * 36) * 512 + q * 4;
    float  s  = 0.f;
    float4 m1 = make_float4(0.f, 0.f, 0.f, 0.f);
    float4 m2 = make_float4(0.f, 0.f, 0.f, 0.f);
    #pragma unroll 6
    for (int i = 0; i < 36; ++i) {
        float  rp = rr1[ks * 36 + i];
        float4 v  = *(const float4*)(vb + i * 512);
        s += rp;
        m1.x += rp * v.x;       m1.y += rp * v.y;
        m1.z += rp * v.z;       m1.w += rp * v.w;
        m2.x += rp * v.x * v.x; m2.y += rp * v.y * v.y;
        m2.z += rp * v.z * v.z; m2.w += rp * v.w * v.w;
        __half2 ha  = __floats2half2_rn(v.x, v.y);
        __half2 hbv = __floats2half2_rn(v.z, v.w);
        uint2 st;
        st.x = *(unsigned int*)&ha;
        st.y = *(unsigned int*)&hbv;
        *(uint2*)(hb + i * 512) = st;
    }
    lm1[tid] = m1; lm2[tid] = m2; lss[tid] = s;
    __syncthreads();

    float lv2 = 0.f, cost_o = 0.f;
    if (tid < 128) {
        float4 a, b;
        a = lm1[tid];       b = lm1[128 + tid];
        m1 = make_float4(a.x + b.x, a.y + b.y, a.z + b.z, a.w + b.w);
        a = lm1[256 + tid]; b = lm1[384 + tid];
        m1.x += a.x + b.x; m1.y += a.y + b.y; m1.z += a.z + b.z; m1.w += a.w + b.w;
        a = lm2[tid];       b = lm2[128 + tid];
        m2 = make_float4(a.x + b.x, a.y + b.y, a.z + b.z, a.w + b.w);
        a = lm2[256 + tid]; b = lm2[384 + tid];
        m2.x += a.x + b.x; m2.y += a.y + b.y; m2.z += a.z + b.z; m2.w += a.w + b.w;
        s = lss[tid] + lss[128 + tid] + lss[256 + tid] + lss[384 + tid];

        float denom = s + EPSF;
        float4 mean = make_float4(m1.x/denom, m1.y/denom, m1.z/denom, m1.w/denom);
        float4 var;
        var.x = fmaxf(m2.x/denom - mean.x*mean.x, 1e-30f);
        var.y = fmaxf(m2.y/denom - mean.y*mean.y, 1e-30f);
        var.z = fmaxf(m2.z/denom - mean.z*mean.z, 1e-30f);
        var.w = fmaxf(m2.w/denom - mean.w*mean.w, 1e-30f);
        float4 i2 = make_float4(0.5f/var.x, 0.5f/var.y, 0.5f/var.z, 0.5f/var.w);
        ml[tid] = mean; il[tid] = i2;
        float lve = logf(var.x+EPSF)+logf(var.y+EPSF)+logf(var.z+EPSF)+logf(var.w+EPSF);
        float l2  = logf(TWO_PI*var.x)+logf(TWO_PI*var.y)+logf(TWO_PI*var.z)+logf(TWO_PI*var.w);
        lve += __shfl_xor(lve, 1); lve += __shfl_xor(lve, 2);
        l2  += __shfl_xor(l2, 1);  l2  += __shfl_xor(l2, 2);
        lv2 = l2;
        cost_o = (16.f * beta_v[o] + 0.5f * lve) * s * LNF;
        if (c4 == 0) costl[o] = cost_o;
    }
    __syncthreads();
    if (tid < 128) {
        float cm = 0.f;
        #pragma unroll
        for (int i = 0; i < O; ++i) cm += costl[i];
        cm *= (1.f / 32.f);
        float sq = 0.f;
        #pragma unroll
        for (int i = 0; i < O; ++i) { float d = costl[i] - cm; sq += d * d; }
        float cstd = sqrtf(sq * (1.f / 32.f));
        float aj = 1.f / (1.f + expf(-lam * (beta_a[o] + (cm - cost_o) / (cstd + EPSF))));
        if (c4 == 0) zl[o] = logf(aj + EPSF) - 0.5f * lv2;
    }
    __syncthreads();

    // zz pass (fp32 re-read, L2/L3-warm)
    {
        float4 mean = ml[q];
        float4 iv   = il[q];
        float  zp   = zl[o];
        #pragma unroll 6
        for (int i = 0; i < 36; ++i) {
            float4 v = *(const float4*)(vb + i * 512);
            float dx = v.x - mean.x, dy = v.y - mean.y;
            float dz = v.z - mean.z, dw = v.w - mean.w;
            float t = dx*dx*iv.x + dy*dy*iv.y + dz*dz*iv.z + dw*dw*iv.w;
            t += __shfl_xor(t, 1); t += __shfl_xor(t, 2);   // 16 pose comps
            if (c4 == 0) zzl[(ks * 36 + i) * O + o] = zp - t;
        }
    }
    __syncthreads();
    float4* dst = (float4*)(g_zz + (size_t)bp * (KTOT * O));
    for (int f = tid; f < KTOT * O / 4; f += 512)
        dst[f] = ((float4*)zzl)[f];
}

// ============ M16: full m_step from fp16 votes + rr' (grid 400) =============
// 512 thr: tid = ks*64 + qp, ks=0..7 (18 rows each), qp = o*2 + h (8 comps).
template<bool LAST>
__global__ __launch_bounds__(512)
void m16_kernel(const __half* __restrict__ hv,
                const float* __restrict__ beta_v, const float* __restrict__ beta_a,
                float* __restrict__ out, float lam)
{
    __shared__ __align__(16) float rrp[KTOT*O];   // 18 KB; reused as zzl
    __shared__ float4 lm1[1024];                  // 16 KB
    __shared__ float4 lm2[1024];                  // 16 KB
    __shared__ float  lss[512];
    __shared__ float4 rm1[128];
    __shared__ float4 rm2[128];
    __shared__ float  rsq[64];
    __shared__ float4 ml[128];
    __shared__ float4 il[128];
    __shared__ float  zl[O];
    __shared__ float  costl[O];

    const int tid = threadIdx.x;
    const int bp  = blockIdx.x;
    const int ks  = tid >> 6;
    const int qp  = tid & 63;
    const int o   = qp >> 1;
    const int h   = qp & 1;

    // stage rr'
    for (int f = tid; f < KTOT * O / 4; f += 512)
        ((float4*)rrp)[f] = ((const float4*)(g_rrp + (size_t)bp * (KTOT * O)))[f];
    __syncthreads();

    const __half* vb = hv + (size_t)bp * VSZ + (size_t)(ks * 18) * 512 + qp * 8;
    float s = 0.f;
    float m1[8], m2[8];
    #pragma unroll
    for (int j = 0; j < 8; ++j) { m1[j] = 0.f; m2[j] = 0.f; }
    #pragma unroll 6
    for (int i = 0; i < 18; ++i) {
        float rp = rrp[(ks * 18 + i) * O + o];
        uint4 u4 = *(const uint4*)(vb + i * 512);
        float f[8]; up8(u4, f);
        s += rp;
        #pragma unroll
        for (int j = 0; j < 8; ++j) {
            m1[j] += rp * f[j];
            m2[j] += rp * f[j] * f[j];
        }
    }
    lm1[tid*2]   = make_float4(m1[0], m1[1], m1[2], m1[3]);
    lm1[tid*2+1] = make_float4(m1[4], m1[5], m1[6], m1[7]);
    lm2[tid*2]   = make_float4(m2[0], m2[1], m2[2], m2[3]);
    lm2[tid*2+1] = make_float4(m2[4], m2[5], m2[6], m2[7]);
    lss[tid] = s;
    __syncthreads();

    if (tid < 64) {
        #pragma unroll
        for (int j = 0; j < 2; ++j) {
            float4 a = lm1[tid*2+j];
            float4 bq = lm2[tid*2+j];
            #pragma unroll
            for (int w = 1; w < 8; ++w) {
                float4 x = lm1[(w*64+tid)*2+j];
                float4 y = lm2[(w*64+tid)*2+j];
                a.x += x.x; a.y += x.y; a.z += x.z; a.w += x.w;
                bq.x += y.x; bq.y += y.y; bq.z += y.z; bq.w += y.w;
            }
            rm1[tid*2+j] = a;    // index = o*4 + (h*2+j) == (o,c4) layout
            rm2[tid*2+j] = bq;
        }
        float sr = 0.f;
        #pragma unroll
        for (int w = 0; w < 8; ++w) sr += lss[w*64+tid];
        rsq[tid] = sr;
    }
    __syncthreads();

    float lv2 = 0.f, cost_o = 0.f;
    const int of = tid >> 2, c4 = tid & 3;     // finish-phase map (tid<128)
    if (tid < 128) {
        float4 fm1 = rm1[tid], fm2 = rm2[tid];
        float  fs  = rsq[of * 2];
        float denom = fs + EPSF;
        float4 mean = make_float4(fm1.x/denom, fm1.y/denom, fm1.z/denom, fm1.w/denom);
        float4 var;
        var.x = fmaxf(fm2.x/denom - mean.x*mean.x, 1e-30f);
        var.y = fmaxf(fm2.y/denom - mean.y*mean.y, 1e-30f);
        var.z = fmaxf(fm2.z/denom - mean.z*mean.z, 1e-30f);
        var.w = fmaxf(fm2.w/denom - mean.w*mean.w, 1e-30f);
        float4 i2 = make_float4(0.5f/var.x, 0.5f/var.y, 0.5f/var.z, 0.5f/var.w);
        ml[tid] = mean; il[tid] = i2;
        float lve = logf(var.x+EPSF)+logf(var.y+EPSF)+logf(var.z+EPSF)+logf(var.w+EPSF);
        float l2  = logf(TWO_PI*var.x)+logf(TWO_PI*var.y)+logf(TWO_PI*var.z)+logf(TWO_PI*var.w);
        lve += __shfl_xor(lve, 1); lve += __shfl_xor(lve, 2);
        l2  += __shfl_xor(l2, 1);  l2  += __shfl_xor(l2, 2);
        lv2 = l2;
        cost_o = (16.f * beta_v[of] + 0.5f * lve) * fs * LNF;
        if (c4 == 0) costl[of] = cost_o;
    }
    __syncthreads();
    if (tid < 128) {
        float cm = 0.f;
        #pragma unroll
        for (int i = 0; i < O; ++i) cm += costl[i];
        cm *= (1.f / 32.f);
        float sq = 0.f;
        #pragma unroll
        for (int i = 0; i < O; ++i) { float d = costl[i] - cm; sq += d * d; }
        float cstd = sqrtf(sq * (1.f / 32.f));
        float aj = 1.f / (1.f + expf(-lam * (beta_a[of] + (cm - cost_o) / (cstd + EPSF))));
        if (LAST) {
            ((float4*)out)[bp * 128 + tid] = ml[tid];
            if (c4 == 0) out[(size_t)NBP * 512 + bp * O + of] = aj;
        } else {
            if (c4 == 0) zl[of] = logf(aj + EPSF) - 0.5f * lv2;
        }
    }
    if (LAST) return;
    __syncthreads();

    // zz pass (fp16 re-read, L2/L3-warm); zzl aliases rrp
    {
        float4 mA = ml[o*4 + h*2], mB = ml[o*4 + h*2 + 1];
        float4 iA = il[o*4 + h*2], iB = il[o*4 + h*2 + 1];
        float  zp = zl[o];
        #pragma unroll 6
        for (int i = 0; i < 18; ++i) {
            uint4 u4 = *(const uint4*)(vb + i * 512);
            float f[8]; up8(u4, f);
            float d0 = f[0]-mA.x, d1 = f[1]-mA.y, d2 = f[2]-mA.z, d3 = f[3]-mA.w;
            float d4 = f[4]-mB.x, d5 = f[5]-mB.y, d6 = f[6]-mB.z, d7 = f[7]-mB.w;
            float t = d0*d0*iA.x + d1*d1*iA.y + d2*d2*iA.z + d3*d3*iA.w
                    + d4*d4*iB.x + d5*d5*iB.y + d6*d6*iB.z + d7*d7*iB.w;
            t += __shfl_xor(t, 1);
            if (h == 0) rrp[(ks * 18 + i) * O + o] = zp - t;
        }
    }
    __syncthreads();
    float4* dst = (float4*)(g_zz + (size_t)bp * (KTOT * O));
    for (int f = tid; f < KTOT * O / 4; f += 512)
        dst[f] = ((float4*)rrp)[f];
}

// ============ E: segment softmax, writes rr' = rr * act =============
__global__ __launch_bounds__(256)
void e_kernel(const float* __restrict__ acts)
{
    const int tid = threadIdx.x;
    const int u   = blockIdx.x;
    const int b   = u / (CS * CS * 2);
    int r = u - b * (CS * CS * 2);
    const int child = r >> 1, half = r & 1;
    const int cr = child / CS, cl = child - cr * CS;
    const int cc = half * 8 + (tid >> 5), o = tid & 31;

    float zz[9];
    float vmax = -1e30f;
    #pragma unroll
    for (int kr = 0; kr < 3; ++kr) {
        int pr_ = cr - kr;
        #pragma unroll
        for (int kc = 0; kc < 3; ++kc) {
            int pc_ = cl - kc, si = kr * 3 + kc;
            float z = -1e30f;
            if (pr_ >= 0 && pr_ < P && pc_ >= 0 && pc_ < P) {
                int bpp = b * P2 + pr_ * P + pc_;
                z = g_zz[(size_t)bpp * (KTOT * O) + (si * CCAPS + cc) * O + o];
            }
            zz[si] = z;
            vmax = fmaxf(vmax, z);
        }
    }
    vmax = fmaxf(vmax, __shfl_xor(vmax, 1));
    vmax = fmaxf(vmax, __shfl_xor(vmax, 2));
    vmax = fmaxf(vmax, __shfl_xor(vmax, 4));
    vmax = fmaxf(vmax, __shfl_xor(vmax, 8));
    vmax = fmaxf(vmax, __shfl_xor(vmax, 16));

    float ps = 0.f;
    #pragma unroll
    for (int si = 0; si < 9; ++si) {
        float e = (zz[si] > -1e29f) ? expf(zz[si] - vmax) : 0.f;
        zz[si] = e;
        ps += e;
    }
    ps += __shfl_xor(ps, 1);
    ps += __shfl_xor(ps, 2);
    ps += __shfl_xor(ps, 4);
    ps += __shfl_xor(ps, 8);
    ps += __shfl_xor(ps, 16);
    float inv = 1.f / ps;

    #pragma unroll
    for (int kr = 0; kr < 3; ++kr) {
        int pr_ = cr - kr;
        #pragma unroll
        for (int kc = 0; kc < 3; ++kc) {
            int pc_ = cl - kc, si = kr * 3 + kc;
            if (pr_ >= 0 && pr_ < P && pc_ >= 0 && pc_ < P) {
                int bpp = b * P2 + pr_ * P + pc_;
                float av = acts[bpp * KTOT + si * CCAPS + cc];
                g_rrp[(size_t)bpp * (KTOT * O) + (si * CCAPS + cc) * O + o]
                    = zz[si] * inv * av;
            }
        }
    }
}

extern "C" void kernel_launch(void* const* d_in, const int* in_sizes, int n_in,
                              void* d_out, int out_size, void* d_ws, size_t ws_size,
                              hipStream_t stream)
{
    (void)in_sizes; (void)n_in; (void)out_size; (void)ws_size;

    const float* votes = (const float*)d_in[0];
    const float* acts  = (const float*)d_in[1];
    const float* bv    = (const float*)d_in[2];
    const float* ba    = (const float*)d_in[3];
    float* out = (float*)d_out;
    __half* hv = (__half*)d_ws;          // 59 MB fp16 votes copy

    v400_kernel<<<dim3(NBP), dim3(512), 0, stream>>>(votes, acts, hv, bv, ba, LAM0);
    e_kernel<<<dim3(EUNITS), dim3(256), 0, stream>>>(acts);
    m16_kernel<false><<<dim3(NBP), dim3(512), 0, stream>>>(hv, bv, ba, out, LAM1);
    e_kernel<<<dim3(EUNITS), dim3(256), 0, stream>>>(acts);
    m16_kernel<true ><<<dim3(NBP), dim3(512), 0, stream>>>(hv, bv, ba, out, LAM2);
}